// Round 3
// baseline (297.702 us; speedup 1.0000x reference)
//
#include <hip/hip_runtime.h>
#include <math.h>

#define T_DIM 64
#define U_DIM 142
#define I_DIM 4500
#define B_DIM 16384
#define K_TOP 10

// Chunked streaming geometry: each block owns (t, chunk-of-256-items).
#define CHW   256                     // items per chunk
#define NCH   18                      // ceil(4500/256); last chunk = 148 items
#define NCELL (T_DIM * NCH)           // 1152 (t,chunk) cells
#define CAPC  48                      // batch slots per cell (mean 14.2, +8.8 sigma)
#define SROW  145                     // LDS column stride (odd -> no bank pattern)

// Workspace layout (ints):
//   [0 .. NCELL)                 per-cell counters
//   [NCELL]                      overflow counter
//   [NCELL+1 .. +B_DIM)          overflow batch list
//   [OVF_END .. +NCELL*CAPC)     per-cell batch lists
#define CNT_OFF   0
#define OVFC_OFF  (NCELL)
#define OVF_OFF   (NCELL + 1)
#define LIST_OFF  (OVF_OFF + B_DIM)
#define WS_INTS   (LIST_OFF + NCELL * CAPC)
#define WS_BYTES  ((size_t)WS_INTS * sizeof(int))

// ---------------------------------------------------------------------------
// Phase 0: zero counters (1153 ints). One block, grid-stride.
// ---------------------------------------------------------------------------
__global__ void zero_ws(int* __restrict__ ws)
{
    for (int k = threadIdx.x; k <= NCELL; k += 256) ws[CNT_OFF + k] = 0;
}

// ---------------------------------------------------------------------------
// Phase 1: bin batches by (t, item-chunk). 1152 counters -> low contention.
// ---------------------------------------------------------------------------
__global__ __launch_bounds__(256) void build_index(
    const int* __restrict__ time_id,
    const int* __restrict__ item_id,
    int*       __restrict__ ws)
{
    const int b = blockIdx.x * 256 + threadIdx.x;
    if (b >= B_DIM) return;
    const int t = time_id[b];
    const int c = item_id[b] >> 8;            // CHW = 256
    const int cell = t * NCH + c;
    const int j = atomicAdd(&ws[CNT_OFF + cell], 1);
    if (j < CAPC) {
        ws[LIST_OFF + cell * CAPC + j] = b;
    } else {
        const int k = atomicAdd(&ws[OVFC_OFF], 1);   // statistically never
        ws[OVF_OFF + k] = b;
    }
}

// ---------------------------------------------------------------------------
// Phase 2 (the workhorse): block = (t, chunk). Stream the 142 x W panel of
// qos coalesced (float4/lane, one wave per row group), scatter the needed
// columns into LDS via per-lane ownership lists, then run the proven
// wave-per-batch top-10 selection on LDS-resident columns.
// Lane-list overflow (>8 batches in one 4-item window): slot left garbage,
// batch pushed to overflow; cleanup kernel (launched after) overwrites out[b].
// ---------------------------------------------------------------------------
__global__ __launch_bounds__(256) void ucf_stream(
    const float* __restrict__ qos,       // [T,U,I]
    const float* __restrict__ user_avg,  // [T,U]
    const float* __restrict__ user_sim,  // [U,U]
    const int*   __restrict__ user_id,   // [B]
    const int*   __restrict__ item_id,   // [B]
    int*         __restrict__ ws,
    float*       __restrict__ out)       // [B]
{
    __shared__ float lds[CAPC * SROW];
    __shared__ int   ls_b[CAPC];
    __shared__ int   ls_u[CAPC];
    __shared__ int   ls_i[CAPC];

    const int cell = blockIdx.x;
    const int t    = cell / NCH;
    const int c    = cell - t * NCH;
    const int i0   = c * CHW;
    const int W    = (I_DIM - i0 < CHW) ? (I_DIM - i0) : CHW;  // 256 or 148 (both %4==0)

    int cnt = ws[CNT_OFF + cell];
    if (cnt > CAPC) cnt = CAPC;
    if (cnt == 0) return;

    const int lane = threadIdx.x & 63;
    const int wid  = threadIdx.x >> 6;

    // Load batch list + per-batch scalars into LDS.
    if (threadIdx.x < cnt) {
        const int b = ws[LIST_OFF + cell * CAPC + threadIdx.x];
        ls_b[threadIdx.x] = b;
        ls_u[threadIdx.x] = user_id[b];
        ls_i[threadIdx.x] = item_id[b];
    }
    __syncthreads();

    // Per-lane ownership lists: lane (im-i0)>>2 owns slot s. Up to 8 packed
    // entries of ((slot<<2)|elem) per lane. Identical across the 4 waves.
    unsigned int pk0 = 0, pk1 = 0;
    int nOwn = 0;
    for (int s = 0; s < cnt; ++s) {
        const int di = ls_i[s] - i0;          // 0..W-1
        if ((di >> 2) == lane) {
            if (nOwn < 8) {
                const unsigned e = (unsigned)((s << 2) | (di & 3));
                if (nOwn < 4) pk0 |= e << (8 * nOwn);
                else          pk1 |= e << (8 * (nOwn - 4));
                ++nOwn;
            } else if (wid == 0) {            // statistically never
                const int k = atomicAdd(&ws[OVFC_OFF], 1);
                ws[OVF_OFF + k] = ls_b[s];
            }
        }
    }

    // Stream the panel: wave w handles rows v = w, w+4, ... Each lane loads
    // one float4 (i0 + lane*4), then scatters its owned slots' elements.
    const float* base = qos + ((size_t)t * U_DIM) * (size_t)I_DIM + i0 + lane * 4;
    const bool doload = (lane * 4) < W;
    for (int v = wid; v < U_DIM; v += 4) {
        float4 q = make_float4(0.f, 0.f, 0.f, 0.f);
        if (doload) q = *(const float4*)(base + (size_t)v * I_DIM);
        for (int e = 0; e < nOwn; ++e) {
            const unsigned pk = (e < 4) ? (pk0 >> (8 * e)) : (pk1 >> (8 * (e - 4)));
            const int s  = (pk >> 2) & 0x3f;
            const int el = pk & 3;
            const float val = (el == 0) ? q.x : (el == 1) ? q.y : (el == 2) ? q.z : q.w;
            lds[s * SROW + v] = val;
        }
    }
    __syncthreads();

    // Selection: wave w handles slots w, w+4, ... Proven (val,idx)-butterfly
    // with post-reduce contribution shuffle; tie -> lower user index.
    const float* arow = user_avg + (size_t)t * U_DIM;
    for (int s = wid; s < cnt; s += 4) {
        const int b = ls_b[s];
        const int u = ls_u[s];
        const float* srow = user_sim + (size_t)u * U_DIM;
        const float* col  = lds + s * SROW;

        float val0, val1, val2 = -INFINITY;
        float con0, con1, con2 = 0.0f;
        {
            const float rv0 = col[lane];
            const float rv1 = col[lane + 64];
            const float a0  = arow[lane];
            const float a1  = arow[lane + 64];
            const float s0  = srow[lane];
            const float s1  = srow[lane + 64];
            val0 = (rv0 > 0.0f) ? s0 : 0.0f;
            con0 = val0 * (rv0 - a0);
            val1 = (rv1 > 0.0f) ? s1 : 0.0f;
            con1 = val1 * (rv1 - a1);
            if (lane + 128 < U_DIM) {
                const float rv2 = col[lane + 128];
                const float a2  = arow[lane + 128];
                const float s2  = srow[lane + 128];
                val2 = (rv2 > 0.0f) ? s2 : 0.0f;
                con2 = val2 * (rv2 - a2);
            }
        }

        float ssum = 0.0f, wsum = 0.0f;
#pragma unroll
        for (int k = 0; k < K_TOP; ++k) {
            float mv = val0; int mk = lane;
            if (val1 > mv) { mv = val1; mk = lane + 64; }
            if (val2 > mv) { mv = val2; mk = lane + 128; }
#pragma unroll
            for (int off = 32; off > 0; off >>= 1) {
                const float ov = __shfl_xor(mv, off, 64);
                const int   ok = __shfl_xor(mk, off, 64);
                if (ov > mv || (ov == mv && ok < mk)) { mv = ov; mk = ok; }
            }
            const int sl = mk >> 6;
            const int wl = mk & 63;
            const float csel = (sl == 0) ? con0 : (sl == 1) ? con1 : con2;
            const float mc = __shfl(csel, wl, 64);
            ssum += mv;
            wsum += mc;
            if (wl == lane) {
                if (sl == 0)      val0 = -INFINITY;
                else if (sl == 1) val1 = -INFINITY;
                else              val2 = -INFINITY;
            }
        }

        if (lane == 0) out[b] = arow[u] + wsum / (ssum + 1e-8f);
    }
}

// ---------------------------------------------------------------------------
// Phase 3: overflow cleanup — direct gather (round-0 proven path) for any
// batch that missed a slot. Grid-stride over the overflow list; exits in
// ~1 us when the list is empty (the expected case).
// ---------------------------------------------------------------------------
__global__ __launch_bounds__(256) void ucf_cleanup(
    const float* __restrict__ qos,
    const float* __restrict__ user_avg,
    const float* __restrict__ user_sim,
    const int*   __restrict__ user_id,
    const int*   __restrict__ item_id,
    const int*   __restrict__ time_id,
    const int*   __restrict__ ws,
    float*       __restrict__ out)
{
    const int lane = threadIdx.x & 63;
    const int wid  = threadIdx.x >> 6;
    const int nw   = gridDim.x * 4;
    const int w0   = blockIdx.x * 4 + wid;
    const int ovfc = ws[OVFC_OFF];

    for (int k = w0; k < ovfc; k += nw) {
        const int b = ws[OVF_OFF + k];
        const int u = user_id[b];
        const int i = item_id[b];
        const int t = time_id[b];
        const float* qcol = qos + ((size_t)t * U_DIM) * (size_t)I_DIM + i;
        const float* srow = user_sim + (size_t)u * U_DIM;
        const float* arow = user_avg + (size_t)t * U_DIM;

        float val0, val1, val2 = -INFINITY;
        float con0, con1, con2 = 0.0f;
        {
            const float rv0 = qcol[(size_t)lane * I_DIM];
            const float rv1 = qcol[(size_t)(lane + 64) * I_DIM];
            val0 = (rv0 > 0.0f) ? srow[lane] : 0.0f;
            con0 = val0 * (rv0 - arow[lane]);
            val1 = (rv1 > 0.0f) ? srow[lane + 64] : 0.0f;
            con1 = val1 * (rv1 - arow[lane + 64]);
            if (lane + 128 < U_DIM) {
                const float rv2 = qcol[(size_t)(lane + 128) * I_DIM];
                val2 = (rv2 > 0.0f) ? srow[lane + 128] : 0.0f;
                con2 = val2 * (rv2 - arow[lane + 128]);
            }
        }
        float ssum = 0.0f, wsum = 0.0f;
#pragma unroll
        for (int kk = 0; kk < K_TOP; ++kk) {
            float mv = val0; int mk = lane;
            if (val1 > mv) { mv = val1; mk = lane + 64; }
            if (val2 > mv) { mv = val2; mk = lane + 128; }
#pragma unroll
            for (int off = 32; off > 0; off >>= 1) {
                const float ov = __shfl_xor(mv, off, 64);
                const int   ok = __shfl_xor(mk, off, 64);
                if (ov > mv || (ov == mv && ok < mk)) { mv = ov; mk = ok; }
            }
            const int sl = mk >> 6;
            const int wl = mk & 63;
            const float csel = (sl == 0) ? con0 : (sl == 1) ? con1 : con2;
            const float mc = __shfl(csel, wl, 64);
            ssum += mv;
            wsum += mc;
            if (wl == lane) {
                if (sl == 0)      val0 = -INFINITY;
                else if (sl == 1) val1 = -INFINITY;
                else              val2 = -INFINITY;
            }
        }
        if (lane == 0) out[b] = arow[u] + wsum / (ssum + 1e-8f);
    }
}

// ---------------------------------------------------------------------------
// Fallback (proven round-0 baseline): used only if workspace is too small.
// ---------------------------------------------------------------------------
__global__ __launch_bounds__(256) void ucf_kernel(
    const float* __restrict__ qos,
    const float* __restrict__ user_avg,
    const float* __restrict__ user_sim,
    const int*   __restrict__ user_id,
    const int*   __restrict__ item_id,
    const int*   __restrict__ time_id,
    float*       __restrict__ out)
{
    const int lane = threadIdx.x & 63;
    const int wid  = threadIdx.x >> 6;
    const int b    = blockIdx.x * 4 + wid;
    if (b >= B_DIM) return;

    const int u = user_id[b];
    const int i = item_id[b];
    const int t = time_id[b];

    const float* qcol = qos + ((size_t)t * U_DIM) * (size_t)I_DIM + i;
    const float* srow = user_sim + (size_t)u * U_DIM;
    const float* arow = user_avg + (size_t)t * U_DIM;

    float val[3];
    float con[3];
#pragma unroll
    for (int j = 0; j < 3; ++j) {
        const int v = lane + j * 64;
        float sv = -INFINITY;
        float cv = 0.0f;
        if (v < U_DIM) {
            const float rv = qcol[(size_t)v * I_DIM];
            const float av = arow[v];
            const float s  = srow[v];
            sv = (rv > 0.0f) ? s : 0.0f;
            cv = sv * (rv - av);
        }
        val[j] = sv;
        con[j] = cv;
    }

    float ssum = 0.0f, wsum = 0.0f;
#pragma unroll
    for (int k = 0; k < K_TOP; ++k) {
        float mv = val[0]; float mc = con[0]; int mk = lane;
        if (val[1] > mv) { mv = val[1]; mc = con[1]; mk = lane + 64; }
        if (val[2] > mv) { mv = val[2]; mc = con[2]; mk = lane + 128; }
#pragma unroll
        for (int off = 32; off > 0; off >>= 1) {
            const float ov = __shfl_xor(mv, off, 64);
            const float oc = __shfl_xor(mc, off, 64);
            const int   ok = __shfl_xor(mk, off, 64);
            if (ov > mv || (ov == mv && ok < mk)) { mv = ov; mc = oc; mk = ok; }
        }
        ssum += mv;
        wsum += mc;
        if ((mk & 63) == lane) {
            const int slot = mk >> 6;
            if (slot == 0)      val[0] = -INFINITY;
            else if (slot == 1) val[1] = -INFINITY;
            else                val[2] = -INFINITY;
        }
    }

    if (lane == 0) {
        out[b] = arow[u] + wsum / (ssum + 1e-8f);
    }
}

extern "C" void kernel_launch(void* const* d_in, const int* in_sizes, int n_in,
                              void* d_out, int out_size, void* d_ws, size_t ws_size,
                              hipStream_t stream) {
    const float* qos  = (const float*)d_in[0];
    const float* uavg = (const float*)d_in[1];
    const float* usim = (const float*)d_in[2];
    const int*   uid  = (const int*)d_in[3];
    const int*   iid  = (const int*)d_in[4];
    const int*   tid  = (const int*)d_in[5];
    // d_in[6] is top_k, fixed at 10 by the problem instance (K_TOP).
    float* out = (float*)d_out;

    if (d_ws != nullptr && ws_size >= WS_BYTES) {
        int* ws = (int*)d_ws;
        zero_ws<<<dim3(1), dim3(256), 0, stream>>>(ws);
        build_index<<<dim3((B_DIM + 255) / 256), dim3(256), 0, stream>>>(tid, iid, ws);
        ucf_stream<<<dim3(NCELL), dim3(256), 0, stream>>>(
            qos, uavg, usim, uid, iid, ws, out);
        ucf_cleanup<<<dim3(16), dim3(256), 0, stream>>>(
            qos, uavg, usim, uid, iid, tid, ws, out);
    } else {
        ucf_kernel<<<dim3(B_DIM / 4), dim3(256), 0, stream>>>(
            qos, uavg, usim, uid, iid, tid, out);
    }
}

// Round 4
// 251.792 us; speedup vs baseline: 1.1823x; 1.1823x over previous
//
#include <hip/hip_runtime.h>
#include <math.h>

#define T_DIM 64
#define U_DIM 142
#define I_DIM 4500
#define B_DIM 16384
#define K_TOP 10

// One wave = TWO batch elements (b and b+8192). All 6 qos line-misses issue
// up-front (independent addresses -> 6 outstanding HBM misses per wave, 2x
// round-0), then the two proven top-10 selections run back-to-back over
// VALU while the misses land. Grid = 2048 blocks x 4 waves = 8192 waves =
// exactly full occupancy (32 waves/CU) in ONE pass.
__global__ __launch_bounds__(256) void ucf2_kernel(
    const float* __restrict__ qos,       // [T,U,I]
    const float* __restrict__ user_avg,  // [T,U]
    const float* __restrict__ user_sim,  // [U,U]
    const int*   __restrict__ user_id,   // [B]
    const int*   __restrict__ item_id,   // [B]
    const int*   __restrict__ time_id,   // [B]
    float*       __restrict__ out)       // [B]
{
    const int lane = threadIdx.x & 63;
    const int wid  = threadIdx.x >> 6;
    const int w    = blockIdx.x * 4 + wid;   // 0..8191
    const int b0   = w;
    const int b1   = w + (B_DIM / 2);

    const int u0 = user_id[b0], u1 = user_id[b1];
    const int i0 = item_id[b0], i1 = item_id[b1];
    const int t0 = time_id[b0], t1 = time_id[b1];

    const float* qcol0 = qos + ((size_t)t0 * U_DIM) * (size_t)I_DIM + i0;
    const float* qcol1 = qos + ((size_t)t1 * U_DIM) * (size_t)I_DIM + i1;

    // ---- issue ALL qos misses first (the expensive random lines) ----
    const float rA0 = qcol0[(size_t)lane * I_DIM];
    const float rA1 = qcol0[(size_t)(lane + 64) * I_DIM];
    const float rB0 = qcol1[(size_t)lane * I_DIM];
    const float rB1 = qcol1[(size_t)(lane + 64) * I_DIM];
    float rA2 = 0.0f, rB2 = 0.0f;
    const bool has2 = (lane + 128) < U_DIM;   // lanes 0..13
    if (has2) {
        rA2 = qcol0[(size_t)(lane + 128) * I_DIM];
        rB2 = qcol1[(size_t)(lane + 128) * I_DIM];
    }

    // ---- cheap cached rows (user_avg, user_sim: tiny, L1/L2-hot) ----
    const float* arow0 = user_avg + (size_t)t0 * U_DIM;
    const float* arow1 = user_avg + (size_t)t1 * U_DIM;
    const float* srow0 = user_sim + (size_t)u0 * U_DIM;
    const float* srow1 = user_sim + (size_t)u1 * U_DIM;

    // ================= batch 0 =================
    {
        float val0, val1, val2 = -INFINITY;
        float con0, con1, con2 = 0.0f;
        {
            const float a0 = arow0[lane];
            const float a1 = arow0[lane + 64];
            const float s0 = srow0[lane];
            const float s1 = srow0[lane + 64];
            val0 = (rA0 > 0.0f) ? s0 : 0.0f;
            con0 = val0 * (rA0 - a0);
            val1 = (rA1 > 0.0f) ? s1 : 0.0f;
            con1 = val1 * (rA1 - a1);
            if (has2) {
                const float a2 = arow0[lane + 128];
                const float s2 = srow0[lane + 128];
                val2 = (rA2 > 0.0f) ? s2 : 0.0f;
                con2 = val2 * (rA2 - a2);
            }
        }
        float ssum = 0.0f, wsum = 0.0f;
#pragma unroll
        for (int k = 0; k < K_TOP; ++k) {
            // local argmax (ascending v, strict > keeps lower v on tie)
            float mv = val0; int mk = lane;
            if (val1 > mv) { mv = val1; mk = lane + 64; }
            if (val2 > mv) { mv = val2; mk = lane + 128; }
            // butterfly max-reduce on (val,idx); tie -> lower user index
#pragma unroll
            for (int off = 32; off > 0; off >>= 1) {
                const float ov = __shfl_xor(mv, off, 64);
                const int   ok = __shfl_xor(mk, off, 64);
                if (ov > mv || (ov == mv && ok < mk)) { mv = ov; mk = ok; }
            }
            const int sl = mk >> 6;
            const int wl = mk & 63;
            const float csel = (sl == 0) ? con0 : (sl == 1) ? con1 : con2;
            const float mc = __shfl(csel, wl, 64);
            ssum += mv;
            wsum += mc;
            if (wl == lane) {
                if (sl == 0)      val0 = -INFINITY;
                else if (sl == 1) val1 = -INFINITY;
                else              val2 = -INFINITY;
            }
        }
        if (lane == 0) out[b0] = arow0[u0] + wsum / (ssum + 1e-8f);
    }

    // ================= batch 1 =================
    {
        float val0, val1, val2 = -INFINITY;
        float con0, con1, con2 = 0.0f;
        {
            const float a0 = arow1[lane];
            const float a1 = arow1[lane + 64];
            const float s0 = srow1[lane];
            const float s1 = srow1[lane + 64];
            val0 = (rB0 > 0.0f) ? s0 : 0.0f;
            con0 = val0 * (rB0 - a0);
            val1 = (rB1 > 0.0f) ? s1 : 0.0f;
            con1 = val1 * (rB1 - a1);
            if (has2) {
                const float a2 = arow1[lane + 128];
                const float s2 = srow1[lane + 128];
                val2 = (rB2 > 0.0f) ? s2 : 0.0f;
                con2 = val2 * (rB2 - a2);
            }
        }
        float ssum = 0.0f, wsum = 0.0f;
#pragma unroll
        for (int k = 0; k < K_TOP; ++k) {
            float mv = val0; int mk = lane;
            if (val1 > mv) { mv = val1; mk = lane + 64; }
            if (val2 > mv) { mv = val2; mk = lane + 128; }
#pragma unroll
            for (int off = 32; off > 0; off >>= 1) {
                const float ov = __shfl_xor(mv, off, 64);
                const int   ok = __shfl_xor(mk, off, 64);
                if (ov > mv || (ov == mv && ok < mk)) { mv = ov; mk = ok; }
            }
            const int sl = mk >> 6;
            const int wl = mk & 63;
            const float csel = (sl == 0) ? con0 : (sl == 1) ? con1 : con2;
            const float mc = __shfl(csel, wl, 64);
            ssum += mv;
            wsum += mc;
            if (wl == lane) {
                if (sl == 0)      val0 = -INFINITY;
                else if (sl == 1) val1 = -INFINITY;
                else              val2 = -INFINITY;
            }
        }
        if (lane == 0) out[b1] = arow1[u1] + wsum / (ssum + 1e-8f);
    }
}

extern "C" void kernel_launch(void* const* d_in, const int* in_sizes, int n_in,
                              void* d_out, int out_size, void* d_ws, size_t ws_size,
                              hipStream_t stream) {
    const float* qos  = (const float*)d_in[0];
    const float* uavg = (const float*)d_in[1];
    const float* usim = (const float*)d_in[2];
    const int*   uid  = (const int*)d_in[3];
    const int*   iid  = (const int*)d_in[4];
    const int*   tid  = (const int*)d_in[5];
    // d_in[6] is top_k, fixed at 10 by the problem instance (K_TOP).
    float* out = (float*)d_out;

    dim3 block(256);                  // 4 waves/block
    dim3 grid(B_DIM / 8);             // 2048 blocks = 8192 waves, 2 batches each
    ucf2_kernel<<<grid, block, 0, stream>>>(qos, uavg, usim, uid, iid, tid, out);
}